// Round 12
// baseline (1272.116 us; speedup 1.0000x reference)
//
#include <hip/hip_runtime.h>
#include <stdint.h>

#define M_DIM 8192
#define K_DIM 4096
#define N_DIM 4096
#define KB (K_DIM / 2)  // bytes per packed-fp4 row: 2048

typedef unsigned char u8;
typedef unsigned int u32;
typedef int i32x4 __attribute__((ext_vector_type(4)));
typedef int i32x8 __attribute__((ext_vector_type(8)));
typedef float f32x4 __attribute__((ext_vector_type(4)));
typedef float float4v __attribute__((ext_vector_type(4)));
typedef u32 u32x2 __attribute__((ext_vector_type(2)));

// sign(v) as fp4 e2m1 code: +1 -> 0x2, -1 -> 0xA, 0 -> 0x0
__device__ __forceinline__ u32 sign_fp4(float v) {
  return v > 0.0f ? 0x2u : (v < 0.0f ? 0xAu : 0x0u);
}

// pack 4 byte-codes (one per byte of v) into 4 nibbles (16-bit result)
__device__ __forceinline__ u32 pk16(u32 v) {
  return (v & 0xFu) | ((v >> 4) & 0xF0u) | ((v >> 8) & 0xF00u) | ((v >> 12) & 0xF000u);
}

// ---------------- fused preprocessing (unchanged) ---------------
__global__ void binarize_fused(const float* __restrict__ x, const float* __restrict__ w,
                               u32* __restrict__ xb, u8* __restrict__ wT) {
  const int tid = threadIdx.x;
  const int bid = blockIdx.x;
  const int r3 = bid % 3;
  if (r3 != 2) {
    __shared__ u8 tile[64][68];
    const int wtile = (bid / 3) * 2 + r3;
    const int bn = (wtile & 63) * 64;
    const int bk = (wtile >> 6) * 64;

#pragma unroll
    for (int it = 0; it < 4; ++it) {
      int idx = tid + it * 256;
      int rr = idx >> 4;
      int c = (idx & 15) * 4;
      float4v v = *(const float4v*)&w[(size_t)(bk + rr) * N_DIM + bn + c];
      tile[c + 0][rr] = (u8)sign_fp4(v.x);
      tile[c + 1][rr] = (u8)sign_fp4(v.y);
      tile[c + 2][rr] = (u8)sign_fp4(v.z);
      tile[c + 3][rr] = (u8)sign_fp4(v.w);
    }
    __syncthreads();
    const int rn = tid >> 2;
    const int cbyte = (tid & 3) * 8;
    const u32* trow = (const u32*)&tile[rn][0];
    u32 q0 = trow[cbyte / 2 + 0];
    u32 q1 = trow[cbyte / 2 + 1];
    u32 q2 = trow[cbyte / 2 + 2];
    u32 q3 = trow[cbyte / 2 + 3];
    u32x2 o;
    o.x = pk16(q0) | (pk16(q1) << 16);
    o.y = pk16(q2) | (pk16(q3) << 16);
    *(u32x2*)&wT[(size_t)(bn + rn) * KB + (bk >> 1) + cbyte] = o;
  } else {
    const int n8 = M_DIM * K_DIM / 8;
    int i = (bid / 3) * 256 + tid;
    const int stride = 2048 * 256;
    for (; i < n8; i += stride) {
      float4v v0 = ((const float4v*)x)[2 * i];
      float4v v1 = ((const float4v*)x)[2 * i + 1];
      u32 wd = sign_fp4(v0.x) | (sign_fp4(v0.y) << 4) | (sign_fp4(v0.z) << 8) |
               (sign_fp4(v0.w) << 12) | (sign_fp4(v1.x) << 16) | (sign_fp4(v1.y) << 20) |
               (sign_fp4(v1.z) << 24) | (sign_fp4(v1.w) << 28);
      xb[i] = wd;
    }
  }
}

// ------------------------------------------------------------------
// 2-blocks/CU fp4 GEMM: BKB=64 B (K-tile = 128 elems), LDS = 64 KiB ->
// two independent blocks co-resident per CU. When one block's waves sit
// at a barrier/drain, the other block's waves feed the MFMA pipe -- the
// cross-phase overlap the 1-block/CU variants couldn't reach.
// Dataflow = round-10 in-place cross-iteration preload, halved K-tile:
// per iter 2 clusters x 16 MFMA, R1(4 reads) under C1, preload(8) under
// C2, stages A(t+1)@top / B(t+2)@MID, MID vmcnt(0), end vmcnt(2).
// pb ping-pongs via 2x-unrolled NAMED register sets (rule #20).
// ------------------------------------------------------------------
#define BM 256
#define BN 256
#define BKB 64            // bytes of K per tile (= 128 fp4 elems)
#define NT (K_DIM / 128)  // 32

__device__ __forceinline__ void gload_lds16(const u8* g, u8* l) {
  __builtin_amdgcn_global_load_lds(
      (const __attribute__((address_space(1))) void*)g,
      (__attribute__((address_space(3))) void*)l, 16, 0, 0);
}

// undef hi half: fp4 f8f6f4 MFMA ignores regs [4:7] of each operand
__device__ __forceinline__ i32x8 pad8(i32x4 v) {
  return __builtin_shufflevector(v, v, 0, 1, 2, 3, -1, -1, -1, -1);
}

// fp4 x fp4, per-lane e8m0 scale byte 0x7F (=1.0), opsel byte 0
__device__ __forceinline__ f32x4 mfma_fp4(i32x4 a, i32x4 b, f32x4 c) {
  return __builtin_amdgcn_mfma_scale_f32_16x16x128_f8f6f4(pad8(a), pad8(b), c, 4, 4, 0, 0x7F, 0,
                                                          0x7F);
}

// One K-tile. PBC: this tile's preloaded b. PBN: next tile's b target.
#define BODY(T, PBC, PBN)                                                      \
  {                                                                            \
    const int buf_ = (T) & 1;                                                  \
    const u8* As_ = &lds[buf_][wr][0];                                         \
    const u8* Bs_ = &lds[buf_][2 + (wc >> 1)][0];                              \
    const u8* AsN_ = &lds[buf_ ^ 1][wr][0];                                    \
    const u8* BsN_ = &lds[buf_ ^ 1][2 + (wc >> 1)][0];                         \
    i32x4 am1_[4];                                                             \
    /* R1: a(mh1) -- consumed by C2, hides under C1 */                         \
    _Pragma("unroll") for (int m = 0; m < 4; ++m) {                            \
      int row = 64 + m * 16 + l15;                                             \
      am1_[m] = *(const i32x4*)&As_[row * 64 + cA];                            \
    }                                                                          \
    if ((T) + 1 < NT) {                                                        \
      const u8* An_ = Ag + (size_t)bm * KB + ((T) + 1) * BKB;                  \
      stage(buf_ ^ 1, 0, An_);                                                 \
      stage(buf_ ^ 1, 1, An_ + (size_t)128 * KB);                              \
    }                                                                          \
    __builtin_amdgcn_sched_barrier(0);                                         \
    /* C1: pa x PBC (both preloaded last iter -- no stall) */                  \
    __builtin_amdgcn_s_setprio(1);                                             \
    _Pragma("unroll") for (int m = 0; m < 4; ++m)                              \
        _Pragma("unroll") for (int n = 0; n < 4; ++n)                          \
            acc[m][n] = mfma_fp4(pa[m], PBC[n], acc[m][n]);                    \
    __builtin_amdgcn_s_setprio(0);                                             \
    /* MID: A(T+1), B(T+1) landed */                                           \
    asm volatile("s_waitcnt vmcnt(0)" ::: "memory");                           \
    __builtin_amdgcn_s_barrier();                                              \
    /* stage B(T+2); preload next tile's pa', pb' (under C2) */                \
    if ((T) + 2 < NT) {                                                        \
      const u8* Bn_ = Btg + (size_t)bn * KB + ((T) + 2) * BKB;                 \
      stage(buf_, 2, Bn_);                                                     \
      stage(buf_, 3, Bn_ + (size_t)128 * KB);                                  \
    }                                                                          \
    if ((T) + 1 < NT) {                                                        \
      _Pragma("unroll") for (int m = 0; m < 4; ++m) {                          \
        int row = m * 16 + l15;                                                \
        pa[m] = *(const i32x4*)&AsN_[row * 64 + cA];                           \
      }                                                                        \
      _Pragma("unroll") for (int n = 0; n < 4; ++n) {                          \
        int row = brow0 + n * 16 + l15;                                        \
        PBN[n] = *(const i32x4*)&BsN_[row * 64 + cA];                          \
      }                                                                        \
    }                                                                          \
    __builtin_amdgcn_sched_barrier(0);                                         \
    /* C2: am1 x PBC */                                                        \
    __builtin_amdgcn_s_setprio(1);                                             \
    _Pragma("unroll") for (int m = 0; m < 4; ++m)                              \
        _Pragma("unroll") for (int n = 0; n < 4; ++n)                          \
            acc[4 + m][n] = mfma_fp4(am1_[m], PBC[n], acc[4 + m][n]);          \
    __builtin_amdgcn_s_setprio(0);                                             \
    if ((T) + 2 < NT)                                                          \
      asm volatile("s_waitcnt vmcnt(2)" ::: "memory");                         \
    else                                                                       \
      asm volatile("s_waitcnt vmcnt(0)" ::: "memory");                         \
    __builtin_amdgcn_s_barrier();                                              \
  }

__global__ __launch_bounds__(512, 4) void gemm_bin_fp4(const u8* __restrict__ Ag,
                                                       const u8* __restrict__ Btg,
                                                       float* __restrict__ C) {
  // slots: 0 = A rows[0,128), 1 = A rows[128,256), 2 = Bt[0,128), 3 = Bt[128,256)
  // each slot 128 rows x 64 B = 8 KiB; 2 bufs x 4 slots = 64 KiB -> 2 blocks/CU.
  __shared__ u8 lds[2][4][128 * 64];

  const int tid = threadIdx.x;
  const int lane = tid & 63;
  const int wid = tid >> 6;  // 0..7
  const int wr = wid >> 2;   // 0..1 (M half)
  const int wc = wid & 3;    // 0..3 (N quarter)

  // XCD-aware swizzle, nwg = 512 (divisible by 8 -> bijective)
  const int b = blockIdx.x;
  const int sw = (b & 7) * (gridDim.x >> 3) + (b >> 3);
  const int tiles_n = N_DIM / BN;  // 16
  const int bm = (sw / tiles_n) * BM;
  const int bn = (sw % tiles_n) * BN;

  const int l15 = lane & 15;
  const int g4 = lane >> 4;
  const int brow0 = (wc & 1) * 64;
  // read-side swizzled col (lane-constant): (g4 ^ ((row>>1)&3))<<4 with
  // (row>>1)&3 == (l15>>1)&3 for all fragment rows (m*16 ≡ 0 mod 8)
  const int cA = ((g4 ^ ((l15 >> 1) & 3)) << 4);
  // write-side pre-swizzled source col: row_local = wid*16 + (lane>>2),
  // (row>>1)&3 == (lane>>3)&3 (wid*16 ≡ 0 mod 8)
  const int swz_src = (((lane & 3) ^ ((lane >> 3) & 3)) << 4);

  // stage one 128-row x 64-B half-tile: ONE gload per wave (8 waves x 16 rows)
  auto stage = [&](int buf, int slot, const u8* gbase) {
    const u8* g = gbase + (size_t)(wid * 16 + (lane >> 2)) * KB + swz_src;
    gload_lds16(g, &lds[buf][slot][wid * 1024]);
  };

  f32x4 acc[8][4] = {};

  // ---- prologue: tile0 (A+B) + B(1) = 6 gloads ----
  {
    const u8* Abase = Ag + (size_t)bm * KB;
    const u8* Bbase = Btg + (size_t)bn * KB;
    stage(0, 0, Abase);
    stage(0, 1, Abase + (size_t)128 * KB);
    stage(0, 2, Bbase);
    stage(0, 3, Bbase + (size_t)128 * KB);
    stage(1, 2, Bbase + BKB);
    stage(1, 3, Bbase + (size_t)128 * KB + BKB);
  }
  asm volatile("s_waitcnt vmcnt(2)" ::: "memory");  // tile0 landed; B(1) in flight
  __builtin_amdgcn_s_barrier();

  // cross-iteration preload registers (pa in place; pb ping-pongs A/B)
  i32x4 pa[4], pbA[4], pbB[4];
  {
    const u8* As0 = &lds[0][wr][0];
    const u8* Bs0 = &lds[0][2 + (wc >> 1)][0];
#pragma unroll
    for (int m = 0; m < 4; ++m) {
      int row = m * 16 + l15;
      pa[m] = *(const i32x4*)&As0[row * 64 + cA];
    }
#pragma unroll
    for (int n = 0; n < 4; ++n) {
      int row = brow0 + n * 16 + l15;
      pbA[n] = *(const i32x4*)&Bs0[row * 64 + cA];
    }
  }

  for (int t = 0; t < NT; t += 2) {
    BODY(t, pbA, pbB);
    BODY(t + 1, pbB, pbA);
  }

  // ---- epilogue: C/D layout col = lane&15, row = (lane>>4)*4 + reg ----
  const int crow0 = bm + wr * 128;
  const int ccol0 = bn + wc * 64;
#pragma unroll
  for (int m = 0; m < 8; ++m)
#pragma unroll
    for (int n = 0; n < 4; ++n)
#pragma unroll
      for (int j = 0; j < 4; ++j)
        C[(size_t)(crow0 + m * 16 + g4 * 4 + j) * N_DIM + ccol0 + n * 16 + l15] = acc[m][n][j];
}

// -------- naive fallback (only if workspace is too small) --------
__global__ void naive_bin_gemm(const float* __restrict__ X, const float* __restrict__ W,
                               float* __restrict__ C) {
  int j = blockIdx.x * blockDim.x + threadIdx.x;
  int i = blockIdx.y;
  if (j >= N_DIM) return;
  float s = 0.0f;
  for (int k = 0; k < K_DIM; ++k) {
    float xv = X[(size_t)i * K_DIM + k];
    float wv = W[(size_t)k * N_DIM + j];
    float sx = (float)((xv > 0.0f) - (xv < 0.0f));
    float sw = (float)((wv > 0.0f) - (wv < 0.0f));
    s += sx * sw;
  }
  C[(size_t)i * N_DIM + j] = s;
}

extern "C" void kernel_launch(void* const* d_in, const int* in_sizes, int n_in,
                              void* d_out, int out_size, void* d_ws, size_t ws_size,
                              hipStream_t stream) {
  const float* x = (const float*)d_in[0];  // [M][K]
  const float* w = (const float*)d_in[1];  // [K][N]
  float* out = (float*)d_out;              // [M][N]

  const size_t xb_bytes = (size_t)M_DIM * KB;  // 16.8 MB
  const size_t wt_bytes = (size_t)N_DIM * KB;  // 8.4 MB

  if (ws_size >= xb_bytes + wt_bytes) {
    u8* xb = (u8*)d_ws;
    u8* wt = (u8*)((char*)d_ws + xb_bytes);

    binarize_fused<<<6144, 256, 0, stream>>>(x, w, (u32*)xb, wt);

    const int grid = (M_DIM / BM) * (N_DIM / BN);  // 32 * 16 = 512
    gemm_bin_fp4<<<grid, 512, 0, stream>>>(xb, wt, out);
  } else {
    naive_bin_gemm<<<dim3(N_DIM / 256, M_DIM), dim3(256), 0, stream>>>(x, w, out);
  }
}

// Round 13
// 167.321 us; speedup vs baseline: 7.6028x; 7.6028x over previous
//
#include <hip/hip_runtime.h>
#include <stdint.h>

#define M_DIM 8192
#define K_DIM 4096
#define N_DIM 4096
#define KB (K_DIM / 2)  // bytes per packed-fp4 row: 2048

typedef unsigned char u8;
typedef unsigned int u32;
typedef int i32x4 __attribute__((ext_vector_type(4)));
typedef int i32x8 __attribute__((ext_vector_type(8)));
typedef float f32x4 __attribute__((ext_vector_type(4)));
typedef float float4v __attribute__((ext_vector_type(4)));
typedef u32 u32x2 __attribute__((ext_vector_type(2)));

// sign(v) as fp4 e2m1 code: +1 -> 0x2, -1 -> 0xA, 0 -> 0x0
__device__ __forceinline__ u32 sign_fp4(float v) {
  return v > 0.0f ? 0x2u : (v < 0.0f ? 0xAu : 0x0u);
}

// pack 4 byte-codes (one per byte of v) into 4 nibbles (16-bit result)
__device__ __forceinline__ u32 pk16(u32 v) {
  return (v & 0xFu) | ((v >> 4) & 0xF0u) | ((v >> 8) & 0xF00u) | ((v >> 12) & 0xF000u);
}

// ---------------- fused preprocessing (unchanged) ---------------
__global__ void binarize_fused(const float* __restrict__ x, const float* __restrict__ w,
                               u32* __restrict__ xb, u8* __restrict__ wT) {
  const int tid = threadIdx.x;
  const int bid = blockIdx.x;
  const int r3 = bid % 3;
  if (r3 != 2) {
    __shared__ u8 tile[64][68];
    const int wtile = (bid / 3) * 2 + r3;
    const int bn = (wtile & 63) * 64;
    const int bk = (wtile >> 6) * 64;

#pragma unroll
    for (int it = 0; it < 4; ++it) {
      int idx = tid + it * 256;
      int rr = idx >> 4;
      int c = (idx & 15) * 4;
      float4v v = *(const float4v*)&w[(size_t)(bk + rr) * N_DIM + bn + c];
      tile[c + 0][rr] = (u8)sign_fp4(v.x);
      tile[c + 1][rr] = (u8)sign_fp4(v.y);
      tile[c + 2][rr] = (u8)sign_fp4(v.z);
      tile[c + 3][rr] = (u8)sign_fp4(v.w);
    }
    __syncthreads();
    const int rn = tid >> 2;
    const int cbyte = (tid & 3) * 8;
    const u32* trow = (const u32*)&tile[rn][0];
    u32 q0 = trow[cbyte / 2 + 0];
    u32 q1 = trow[cbyte / 2 + 1];
    u32 q2 = trow[cbyte / 2 + 2];
    u32 q3 = trow[cbyte / 2 + 3];
    u32x2 o;
    o.x = pk16(q0) | (pk16(q1) << 16);
    o.y = pk16(q2) | (pk16(q3) << 16);
    *(u32x2*)&wT[(size_t)(bn + rn) * KB + (bk >> 1) + cbyte] = o;
  } else {
    const int n8 = M_DIM * K_DIM / 8;
    int i = (bid / 3) * 256 + tid;
    const int stride = 2048 * 256;
    for (; i < n8; i += stride) {
      float4v v0 = ((const float4v*)x)[2 * i];
      float4v v1 = ((const float4v*)x)[2 * i + 1];
      u32 wd = sign_fp4(v0.x) | (sign_fp4(v0.y) << 4) | (sign_fp4(v0.z) << 8) |
               (sign_fp4(v0.w) << 12) | (sign_fp4(v1.x) << 16) | (sign_fp4(v1.y) << 20) |
               (sign_fp4(v1.z) << 24) | (sign_fp4(v1.w) << 28);
      xb[i] = wd;
    }
  }
}

// ------------------------------------------------------------------
// m97-structure fp4 GEMM: 128x128 tile, 4 waves (2x2, 64x64/wave),
// SINGLE-buffer 32 KiB LDS -> 4 blocks/CU (16 waves/CU). Cross-block
// phase desync (m114 mechanism) overlaps one block's vmcnt drain with
// other blocks' MFMA/LDS work — the overlap in-block scheduling never
// delivered. acc = 16 f32x4 = 64 VGPR -> fits the 128-VGPR budget at
// 4 waves/SIMD (round-12 spill fix). K-tile = 256 elems = 128-B rows,
// verified XOR swizzle, 16x16x128 fp4 MFMA, XCD-aware block swizzle.
// ------------------------------------------------------------------
#define BM 128
#define BN 128
#define BKB 128           // bytes of K per tile (= 256 fp4 elems)
#define NT (K_DIM / 256)  // 16

__device__ __forceinline__ void gload_lds16(const u8* g, u8* l) {
  __builtin_amdgcn_global_load_lds(
      (const __attribute__((address_space(1))) void*)g,
      (__attribute__((address_space(3))) void*)l, 16, 0, 0);
}

// undef hi half: fp4 f8f6f4 MFMA ignores regs [4:7] of each operand
__device__ __forceinline__ i32x8 pad8(i32x4 v) {
  return __builtin_shufflevector(v, v, 0, 1, 2, 3, -1, -1, -1, -1);
}

// fp4 x fp4, per-lane e8m0 scale byte 0x7F (=1.0), opsel byte 0
__device__ __forceinline__ f32x4 mfma_fp4(i32x4 a, i32x4 b, f32x4 c) {
  return __builtin_amdgcn_mfma_scale_f32_16x16x128_f8f6f4(pad8(a), pad8(b), c, 4, 4, 0, 0x7F, 0,
                                                          0x7F);
}

__global__ __launch_bounds__(256, 4) void gemm_bin_fp4(const u8* __restrict__ Ag,
                                                       const u8* __restrict__ Btg,
                                                       float* __restrict__ C) {
  // single buffer: A 128 rows x 128 B + B 128 rows x 128 B = 32 KiB
  __shared__ u8 As[128 * 128];
  __shared__ u8 Bs[128 * 128];

  const int tid = threadIdx.x;
  const int lane = tid & 63;
  const int wid = tid >> 6;  // 0..3
  const int wr = wid >> 1;   // 0..1 (M half)
  const int wc = wid & 1;    // 0..1 (N half)

  // XCD-aware swizzle, nwg = 2048 (divisible by 8 -> bijective)
  const int b = blockIdx.x;
  const int sw = (b & 7) * (gridDim.x >> 3) + (b >> 3);
  const int tiles_n = N_DIM / BN;  // 32
  const int bm = (sw / tiles_n) * BM;
  const int bn = (sw % tiles_n) * BN;

  const int l15 = lane & 15;
  const int g4 = lane >> 4;
  const int srow = lane >> 3;                      // 0..7
  const int swz_src = (((lane & 7) ^ srow) << 4);  // pre-swizzled byte col

  const u8* Abase = Ag + (size_t)bm * KB;
  const u8* Bbase = Btg + (size_t)bn * KB;

  f32x4 acc[4][4] = {};

  for (int t = 0; t < NT; ++t) {
    const int kt = t * BKB;
    // ---- stage: each wave loads 32 rows of A and 32 rows of B (8 gloads) ----
#pragma unroll
    for (int i = 0; i < 4; ++i) {
      const int row = wid * 32 + i * 8 + srow;  // row&7 == srow
      gload_lds16(Abase + (size_t)row * KB + kt + swz_src, &As[(wid * 32 + i * 8) * 128]);
      gload_lds16(Bbase + (size_t)row * KB + kt + swz_src, &Bs[(wid * 32 + i * 8) * 128]);
    }
    asm volatile("s_waitcnt vmcnt(0)" ::: "memory");
    __builtin_amdgcn_s_barrier();

    // ---- compute: 2 k-halves, 16 MFMA each ----
#pragma unroll
    for (int kk = 0; kk < 2; ++kk) {
      i32x4 af[4], bf[4];
#pragma unroll
      for (int m = 0; m < 4; ++m) {
        int row = wr * 64 + m * 16 + l15;
        int col = (kk * 64 + g4 * 16) ^ ((row & 7) << 4);
        af[m] = *(const i32x4*)&As[row * 128 + col];
      }
#pragma unroll
      for (int n = 0; n < 4; ++n) {
        int row = wc * 64 + n * 16 + l15;
        int col = (kk * 64 + g4 * 16) ^ ((row & 7) << 4);
        bf[n] = *(const i32x4*)&Bs[row * 128 + col];
      }
#pragma unroll
      for (int m = 0; m < 4; ++m)
#pragma unroll
        for (int n = 0; n < 4; ++n)
          acc[m][n] = mfma_fp4(af[m], bf[n], acc[m][n]);
    }
    // all LDS reads consumed (lgkm-waited before MFMAs) -> safe to restage
    __builtin_amdgcn_s_barrier();
  }

  // ---- epilogue: C/D layout col = lane&15, row = (lane>>4)*4 + reg ----
  const int crow0 = bm + wr * 64;
  const int ccol0 = bn + wc * 64;
#pragma unroll
  for (int m = 0; m < 4; ++m)
#pragma unroll
    for (int n = 0; n < 4; ++n)
#pragma unroll
      for (int j = 0; j < 4; ++j)
        C[(size_t)(crow0 + m * 16 + g4 * 4 + j) * N_DIM + ccol0 + n * 16 + l15] = acc[m][n][j];
}

// -------- naive fallback (only if workspace is too small) --------
__global__ void naive_bin_gemm(const float* __restrict__ X, const float* __restrict__ W,
                               float* __restrict__ C) {
  int j = blockIdx.x * blockDim.x + threadIdx.x;
  int i = blockIdx.y;
  if (j >= N_DIM) return;
  float s = 0.0f;
  for (int k = 0; k < K_DIM; ++k) {
    float xv = X[(size_t)i * K_DIM + k];
    float wv = W[(size_t)k * N_DIM + j];
    float sx = (float)((xv > 0.0f) - (xv < 0.0f));
    float sw = (float)((wv > 0.0f) - (wv < 0.0f));
    s += sx * sw;
  }
  C[(size_t)i * N_DIM + j] = s;
}

extern "C" void kernel_launch(void* const* d_in, const int* in_sizes, int n_in,
                              void* d_out, int out_size, void* d_ws, size_t ws_size,
                              hipStream_t stream) {
  const float* x = (const float*)d_in[0];  // [M][K]
  const float* w = (const float*)d_in[1];  // [K][N]
  float* out = (float*)d_out;              // [M][N]

  const size_t xb_bytes = (size_t)M_DIM * KB;  // 16.8 MB
  const size_t wt_bytes = (size_t)N_DIM * KB;  // 8.4 MB

  if (ws_size >= xb_bytes + wt_bytes) {
    u8* xb = (u8*)d_ws;
    u8* wt = (u8*)((char*)d_ws + xb_bytes);

    binarize_fused<<<6144, 256, 0, stream>>>(x, w, (u32*)xb, wt);

    const int grid = (M_DIM / BM) * (N_DIM / BN);  // 64 * 32 = 2048
    gemm_bin_fp4<<<grid, 256, 0, stream>>>(xb, wt, out);
  } else {
    naive_bin_gemm<<<dim3(N_DIM / 256, M_DIM), dim3(256), 0, stream>>>(x, w, out);
  }
}

// Round 14
// 124.666 us; speedup vs baseline: 10.2042x; 1.3422x over previous
//
#include <hip/hip_runtime.h>
#include <stdint.h>

#define M_DIM 8192
#define K_DIM 4096
#define N_DIM 4096
#define KB (K_DIM / 2)  // bytes per packed-fp4 row: 2048

typedef unsigned char u8;
typedef unsigned short u16;
typedef unsigned int u32;
typedef int i32x4 __attribute__((ext_vector_type(4)));
typedef int i32x8 __attribute__((ext_vector_type(8)));
typedef float f32x4 __attribute__((ext_vector_type(4)));
typedef float float4v __attribute__((ext_vector_type(4)));
typedef u32 u32x2 __attribute__((ext_vector_type(2)));

// sign(v) as fp4 e2m1 code: +1 -> 0x2, -1 -> 0xA, 0 -> 0x0
__device__ __forceinline__ u32 sign_fp4(float v) {
  return v > 0.0f ? 0x2u : (v < 0.0f ? 0xAu : 0x0u);
}

// ---------------- fused preprocessing -----------------------------
// bid%3==2 -> X binarize chunk (2048 chunks); else -> W transpose tile
// (4096 tiles). W part: in-register 4x4 k-transpose, u16 nibble-packed
// LDS writes (4 per thread vs 16 ds_write_u8 before).
__global__ void binarize_fused(const float* __restrict__ x, const float* __restrict__ w,
                               u32* __restrict__ xb, u8* __restrict__ wT) {
  const int tid = threadIdx.x;
  const int bid = blockIdx.x;
  const int r3 = bid % 3;
  if (r3 != 2) {
    // ---- W transpose: one 64(k) x 64(n) tile per block ----
    __shared__ u16 tile[64][20];  // [n][k/4] u16, rows padded 16->20
    const int wtile = (bid / 3) * 2 + r3;
    const int bn = (wtile & 63) * 64;
    const int bk = (wtile >> 6) * 64;

    const int r0 = (tid >> 4) * 4;  // k-local base (0..60)
    const int c = (tid & 15) * 4;   // n-local base (0..60)
    const float* wp = &w[(size_t)(bk + r0) * N_DIM + bn + c];
    float4v v0 = *(const float4v*)(wp);
    float4v v1 = *(const float4v*)(wp + N_DIM);
    float4v v2 = *(const float4v*)(wp + 2 * N_DIM);
    float4v v3 = *(const float4v*)(wp + 3 * N_DIM);
#pragma unroll
    for (int n = 0; n < 4; ++n) {
      float e0 = n == 0 ? v0.x : (n == 1 ? v0.y : (n == 2 ? v0.z : v0.w));
      float e1 = n == 0 ? v1.x : (n == 1 ? v1.y : (n == 2 ? v1.z : v1.w));
      float e2 = n == 0 ? v2.x : (n == 1 ? v2.y : (n == 2 ? v2.z : v2.w));
      float e3 = n == 0 ? v3.x : (n == 1 ? v3.y : (n == 2 ? v3.z : v3.w));
      u16 nib = (u16)(sign_fp4(e0) | (sign_fp4(e1) << 4) | (sign_fp4(e2) << 8) |
                      (sign_fp4(e3) << 12));
      tile[c + n][r0 >> 2] = nib;
    }
    __syncthreads();
    // pack phase: thread -> 8 output bytes (16 k) of one n-row
    const int rn = tid >> 2;       // n-local 0..63
    const int seg = tid & 3;       // 0..3, 4 u16 each
    u32 w0 = (u32)tile[rn][seg * 4 + 0] | ((u32)tile[rn][seg * 4 + 1] << 16);
    u32 w1 = (u32)tile[rn][seg * 4 + 2] | ((u32)tile[rn][seg * 4 + 3] << 16);
    u32x2 o;
    o.x = w0;
    o.y = w1;
    *(u32x2*)&wT[(size_t)(bn + rn) * KB + (bk >> 1) + seg * 8] = o;
  } else {
    // ---- X binarize ----
    const int n8 = M_DIM * K_DIM / 8;
    int i = (bid / 3) * 256 + tid;
    const int stride = 2048 * 256;
    for (; i < n8; i += stride) {
      float4v v0 = ((const float4v*)x)[2 * i];
      float4v v1 = ((const float4v*)x)[2 * i + 1];
      u32 wd = sign_fp4(v0.x) | (sign_fp4(v0.y) << 4) | (sign_fp4(v0.z) << 8) |
               (sign_fp4(v0.w) << 12) | (sign_fp4(v1.x) << 16) | (sign_fp4(v1.y) << 20) |
               (sign_fp4(v1.z) << 24) | (sign_fp4(v1.w) << 28);
      xb[i] = wd;
    }
  }
}

// ------------------------------------------------------------------
// Cross-iteration preload (IN-PLACE) 256x256 fp4 GEMM — round-10 verified
// kernel, unchanged. 80 µs / 3437 TF-equiv = the plain-HIP fp4 structure
// ceiling after 7 schedule variants (8ph / 4ph / 2-barrier / preload all
// 80±1; role-stagger, 2-blk/CU, 4-blk/CU regress). acc 128 + frags fit
// 2 waves/SIMD; MID vmcnt(0)+barrier, end barrier with B(t+2) in flight.
// ------------------------------------------------------------------
#define BM 256
#define BN 256
#define BKB 128           // bytes of K per tile (= 256 fp4 elems)
#define NT (K_DIM / 256)  // 16

__device__ __forceinline__ void gload_lds16(const u8* g, u8* l) {
  __builtin_amdgcn_global_load_lds(
      (const __attribute__((address_space(1))) void*)g,
      (__attribute__((address_space(3))) void*)l, 16, 0, 0);
}

// undef hi half: fp4 f8f6f4 MFMA ignores regs [4:7] of each operand
__device__ __forceinline__ i32x8 pad8(i32x4 v) {
  return __builtin_shufflevector(v, v, 0, 1, 2, 3, -1, -1, -1, -1);
}

// fp4 x fp4, per-lane e8m0 scale byte 0x7F (=1.0), opsel byte 0
__device__ __forceinline__ f32x4 mfma_fp4(i32x4 a, i32x4 b, f32x4 c) {
  return __builtin_amdgcn_mfma_scale_f32_16x16x128_f8f6f4(pad8(a), pad8(b), c, 4, 4, 0, 0x7F, 0,
                                                          0x7F);
}

__global__ __launch_bounds__(512, 2) void gemm_bin_fp4(const u8* __restrict__ Ag,
                                                       const u8* __restrict__ Btg,
                                                       float* __restrict__ C) {
  __shared__ u8 lds[2][4][128 * 128];

  const int tid = threadIdx.x;
  const int lane = tid & 63;
  const int wid = tid >> 6;  // 0..7
  const int wr = wid >> 2;   // 0..1 (M half)
  const int wc = wid & 3;    // 0..3 (N quarter)

  const int b = blockIdx.x;
  const int sw = (b & 7) * (gridDim.x >> 3) + (b >> 3);
  const int tiles_n = N_DIM / BN;  // 16
  const int bm = (sw / tiles_n) * BM;
  const int bn = (sw % tiles_n) * BN;

  const int l15 = lane & 15;
  const int g4 = lane >> 4;
  const int brow0 = (wc & 1) * 64;
  const int srow = lane >> 3;
  const int swz_src = (((lane & 7) ^ srow) << 4);

  auto stage = [&](int buf, int slot, const u8* gbase) {
#pragma unroll
    for (int i = 0; i < 2; ++i) {
      const u8* g = gbase + (size_t)(i * 64 + wid * 8 + srow) * KB + swz_src;
      gload_lds16(g, &lds[buf][slot][(i * 64 + wid * 8) * 128]);
    }
  };

  f32x4 acc[8][4] = {};

  {
    const u8* Abase = Ag + (size_t)bm * KB;
    const u8* Bbase = Btg + (size_t)bn * KB;
    stage(0, 0, Abase);
    stage(0, 1, Abase + (size_t)128 * KB);
    stage(0, 2, Bbase);
    stage(0, 3, Bbase + (size_t)128 * KB);
    stage(1, 2, Bbase + BKB);
    stage(1, 3, Bbase + (size_t)128 * KB + BKB);
  }
  asm volatile("s_waitcnt vmcnt(4)" ::: "memory");
  __builtin_amdgcn_s_barrier();

  i32x4 a0[4], b0[4];
  {
    const u8* As0 = &lds[0][wr][0];
    const u8* Bs0 = &lds[0][2 + (wc >> 1)][0];
#pragma unroll
    for (int m = 0; m < 4; ++m) {
      int row = m * 16 + l15;
      a0[m] = *(const i32x4*)&As0[row * 128 + ((g4 * 16) ^ ((row & 7) << 4))];
    }
#pragma unroll
    for (int n = 0; n < 4; ++n) {
      int row = brow0 + n * 16 + l15;
      b0[n] = *(const i32x4*)&Bs0[row * 128 + ((g4 * 16) ^ ((row & 7) << 4))];
    }
  }

  for (int t = 0; t < NT; ++t) {
    const int buf = t & 1;
    const u8* As = &lds[buf][wr][0];
    const u8* Bs = &lds[buf][2 + (wc >> 1)][0];
    const u8* AsN = &lds[buf ^ 1][wr][0];
    const u8* BsN = &lds[buf ^ 1][2 + (wc >> 1)][0];

    i32x4 a1[4], a2[4], a3[4], b1[4];

    // R2: a1(mh0,k1) + b1(*,k1); stage A(t+1)
#pragma unroll
    for (int m = 0; m < 4; ++m) {
      int row = m * 16 + l15;
      a1[m] = *(const i32x4*)&As[row * 128 + ((64 + g4 * 16) ^ ((row & 7) << 4))];
    }
#pragma unroll
    for (int n = 0; n < 4; ++n) {
      int row = brow0 + n * 16 + l15;
      b1[n] = *(const i32x4*)&Bs[row * 128 + ((64 + g4 * 16) ^ ((row & 7) << 4))];
    }
    if (t + 1 < NT) {
      const u8* An = Ag + (size_t)bm * KB + (t + 1) * BKB;
      stage(buf ^ 1, 0, An);
      stage(buf ^ 1, 1, An + (size_t)128 * KB);
    }
    __builtin_amdgcn_sched_barrier(0);

    // C1: a0 x b0
    __builtin_amdgcn_s_setprio(1);
#pragma unroll
    for (int m = 0; m < 4; ++m)
#pragma unroll
      for (int n = 0; n < 4; ++n)
        acc[m][n] = mfma_fp4(a0[m], b0[n], acc[m][n]);
    __builtin_amdgcn_s_setprio(0);
    __builtin_amdgcn_sched_barrier(0);

    // R3: a2(mh1,k0)
#pragma unroll
    for (int m = 0; m < 4; ++m) {
      int row = 64 + m * 16 + l15;
      a2[m] = *(const i32x4*)&As[row * 128 + ((g4 * 16) ^ ((row & 7) << 4))];
    }
    __builtin_amdgcn_sched_barrier(0);

    // C2: a1 x b1
    __builtin_amdgcn_s_setprio(1);
#pragma unroll
    for (int m = 0; m < 4; ++m)
#pragma unroll
      for (int n = 0; n < 4; ++n)
        acc[m][n] = mfma_fp4(a1[m], b1[n], acc[m][n]);
    __builtin_amdgcn_s_setprio(0);

    // MID
    asm volatile("s_waitcnt vmcnt(0)" ::: "memory");
    __builtin_amdgcn_s_barrier();

    // stage B(t+2); R4: a3(mh1,k1)
    if (t + 2 < NT) {
      const u8* Bn = Btg + (size_t)bn * KB + (t + 2) * BKB;
      stage(buf, 2, Bn);
      stage(buf, 3, Bn + (size_t)128 * KB);
    }
#pragma unroll
    for (int m = 0; m < 4; ++m) {
      int row = 64 + m * 16 + l15;
      a3[m] = *(const i32x4*)&As[row * 128 + ((64 + g4 * 16) ^ ((row & 7) << 4))];
    }
    __builtin_amdgcn_sched_barrier(0);

    // C3: a2 x b0
    __builtin_amdgcn_s_setprio(1);
#pragma unroll
    for (int m = 0; m < 4; ++m)
#pragma unroll
      for (int n = 0; n < 4; ++n)
        acc[4 + m][n] = mfma_fp4(a2[m], b0[n], acc[4 + m][n]);
    __builtin_amdgcn_s_setprio(0);
    __builtin_amdgcn_sched_barrier(0);

    // R1': preload tile t+1's a0,b0 IN PLACE
    if (t + 1 < NT) {
#pragma unroll
      for (int m = 0; m < 4; ++m) {
        int row = m * 16 + l15;
        a0[m] = *(const i32x4*)&AsN[row * 128 + ((g4 * 16) ^ ((row & 7) << 4))];
      }
#pragma unroll
      for (int n = 0; n < 4; ++n) {
        int row = brow0 + n * 16 + l15;
        b0[n] = *(const i32x4*)&BsN[row * 128 + ((g4 * 16) ^ ((row & 7) << 4))];
      }
    }
    __builtin_amdgcn_sched_barrier(0);

    // C4: a3 x b1
    __builtin_amdgcn_s_setprio(1);
#pragma unroll
    for (int m = 0; m < 4; ++m)
#pragma unroll
      for (int n = 0; n < 4; ++n)
        acc[4 + m][n] = mfma_fp4(a3[m], b1[n], acc[4 + m][n]);
    __builtin_amdgcn_s_setprio(0);

    __builtin_amdgcn_s_barrier();
  }

  // epilogue: C/D layout col = lane&15, row = (lane>>4)*4 + reg
  const int crow0 = bm + wr * 128;
  const int ccol0 = bn + wc * 64;
#pragma unroll
  for (int m = 0; m < 8; ++m)
#pragma unroll
    for (int n = 0; n < 4; ++n)
#pragma unroll
      for (int j = 0; j < 4; ++j)
        C[(size_t)(crow0 + m * 16 + g4 * 4 + j) * N_DIM + ccol0 + n * 16 + l15] = acc[m][n][j];
}

// -------- naive fallback (only if workspace is too small) --------
__global__ void naive_bin_gemm(const float* __restrict__ X, const float* __restrict__ W,
                               float* __restrict__ C) {
  int j = blockIdx.x * blockDim.x + threadIdx.x;
  int i = blockIdx.y;
  if (j >= N_DIM) return;
  float s = 0.0f;
  for (int k = 0; k < K_DIM; ++k) {
    float xv = X[(size_t)i * K_DIM + k];
    float wv = W[(size_t)k * N_DIM + j];
    float sx = (float)((xv > 0.0f) - (xv < 0.0f));
    float sw = (float)((wv > 0.0f) - (wv < 0.0f));
    s += sx * sw;
  }
  C[(size_t)i * N_DIM + j] = s;
}

extern "C" void kernel_launch(void* const* d_in, const int* in_sizes, int n_in,
                              void* d_out, int out_size, void* d_ws, size_t ws_size,
                              hipStream_t stream) {
  const float* x = (const float*)d_in[0];  // [M][K]
  const float* w = (const float*)d_in[1];  // [K][N]
  float* out = (float*)d_out;              // [M][N]

  const size_t xb_bytes = (size_t)M_DIM * KB;  // 16.8 MB
  const size_t wt_bytes = (size_t)N_DIM * KB;  // 8.4 MB

  if (ws_size >= xb_bytes + wt_bytes) {
    u8* xb = (u8*)d_ws;
    u8* wt = (u8*)((char*)d_ws + xb_bytes);

    binarize_fused<<<6144, 256, 0, stream>>>(x, w, (u32*)xb, wt);

    const int grid = (M_DIM / BM) * (N_DIM / BN);  // 32 * 16 = 512
    gemm_bin_fp4<<<grid, 512, 0, stream>>>(xb, wt, out);
  } else {
    naive_bin_gemm<<<dim3(N_DIM / 256, M_DIM), dim3(256), 0, stream>>>(x, w, out);
  }
}

// Round 15
// 123.299 us; speedup vs baseline: 10.3173x; 1.0111x over previous
//
#include <hip/hip_runtime.h>
#include <stdint.h>

#define M_DIM 8192
#define K_DIM 4096
#define N_DIM 4096
#define KB (K_DIM / 2)  // bytes per packed-fp4 row: 2048

typedef unsigned char u8;
typedef unsigned short u16;
typedef unsigned int u32;
typedef int i32x4 __attribute__((ext_vector_type(4)));
typedef int i32x8 __attribute__((ext_vector_type(8)));
typedef float f32x4 __attribute__((ext_vector_type(4)));
typedef float float4v __attribute__((ext_vector_type(4)));
typedef u32 u32x2 __attribute__((ext_vector_type(2)));

// sign(v) as fp4 e2m1 code: +1 -> 0x2, -1 -> 0xA, 0 -> 0x0
__device__ __forceinline__ u32 sign_fp4(float v) {
  return v > 0.0f ? 0x2u : (v < 0.0f ? 0xAu : 0x0u);
}

// ---------------- fused preprocessing, load-balanced -----------------
// 12288 blocks, each ~16.4 KB of input: bid%3==0 -> W transpose tile
// (4096 tiles of 64x64); else -> X binarize chunk (8192 chunks, 2
// grid-stride iters each). Equal work/block kills the X-tail that made
// the old 2048-chunk split run 4x longer per block than W blocks.
__global__ void binarize_fused(const float* __restrict__ x, const float* __restrict__ w,
                               u32* __restrict__ xb, u8* __restrict__ wT) {
  const int tid = threadIdx.x;
  const int bid = blockIdx.x;
  const int r3 = bid % 3;
  if (r3 == 0) {
    // ---- W transpose: one 64(k) x 64(n) tile per block ----
    __shared__ u16 tile[64][20];  // [n][k/4] u16, rows padded 16->20
    const int wtile = bid / 3;  // 0..4095
    const int bn = (wtile & 63) * 64;
    const int bk = (wtile >> 6) * 64;

    const int r0 = (tid >> 4) * 4;  // k-local base (0..60)
    const int c = (tid & 15) * 4;   // n-local base (0..60)
    const float* wp = &w[(size_t)(bk + r0) * N_DIM + bn + c];
    float4v v0 = *(const float4v*)(wp);
    float4v v1 = *(const float4v*)(wp + N_DIM);
    float4v v2 = *(const float4v*)(wp + 2 * N_DIM);
    float4v v3 = *(const float4v*)(wp + 3 * N_DIM);
#pragma unroll
    for (int n = 0; n < 4; ++n) {
      float e0 = n == 0 ? v0.x : (n == 1 ? v0.y : (n == 2 ? v0.z : v0.w));
      float e1 = n == 0 ? v1.x : (n == 1 ? v1.y : (n == 2 ? v1.z : v1.w));
      float e2 = n == 0 ? v2.x : (n == 1 ? v2.y : (n == 2 ? v2.z : v2.w));
      float e3 = n == 0 ? v3.x : (n == 1 ? v3.y : (n == 2 ? v3.z : v3.w));
      u16 nib = (u16)(sign_fp4(e0) | (sign_fp4(e1) << 4) | (sign_fp4(e2) << 8) |
                      (sign_fp4(e3) << 12));
      tile[c + n][r0 >> 2] = nib;
    }
    __syncthreads();
    // pack phase: thread -> 8 output bytes (16 k) of one n-row
    const int rn = tid >> 2;  // n-local 0..63
    const int seg = tid & 3;  // 0..3, 4 u16 each
    u32 w0 = (u32)tile[rn][seg * 4 + 0] | ((u32)tile[rn][seg * 4 + 1] << 16);
    u32 w1 = (u32)tile[rn][seg * 4 + 2] | ((u32)tile[rn][seg * 4 + 3] << 16);
    u32x2 o;
    o.x = w0;
    o.y = w1;
    *(u32x2*)&wT[(size_t)(bn + rn) * KB + (bk >> 1) + seg * 8] = o;
  } else {
    // ---- X binarize: chunk id 0..8191, 2 grid-stride iters ----
    const int n8 = M_DIM * K_DIM / 8;
    const int chunk = (bid / 3) * 2 + (r3 - 1);  // 0..8191 bijective
    int i = chunk * 256 + tid;
    const int stride = 8192 * 256;
    for (; i < n8; i += stride) {
      float4v v0 = ((const float4v*)x)[2 * i];
      float4v v1 = ((const float4v*)x)[2 * i + 1];
      u32 wd = sign_fp4(v0.x) | (sign_fp4(v0.y) << 4) | (sign_fp4(v0.z) << 8) |
               (sign_fp4(v0.w) << 12) | (sign_fp4(v1.x) << 16) | (sign_fp4(v1.y) << 20) |
               (sign_fp4(v1.z) << 24) | (sign_fp4(v1.w) << 28);
      xb[i] = wd;
    }
  }
}

// ------------------------------------------------------------------
// Cross-iteration preload (IN-PLACE) 256x256 fp4 GEMM — round-10 verified
// kernel, unchanged. 80 µs / 3437 TF-equiv = plain-HIP fp4 structure
// ceiling (7 schedule variants pinned 80±1; stagger/occupancy variants
// regress). acc 128 + frags fit 2 waves/SIMD; MID vmcnt(0)+barrier.
// ------------------------------------------------------------------
#define BM 256
#define BN 256
#define BKB 128           // bytes of K per tile (= 256 fp4 elems)
#define NT (K_DIM / 256)  // 16

__device__ __forceinline__ void gload_lds16(const u8* g, u8* l) {
  __builtin_amdgcn_global_load_lds(
      (const __attribute__((address_space(1))) void*)g,
      (__attribute__((address_space(3))) void*)l, 16, 0, 0);
}

// undef hi half: fp4 f8f6f4 MFMA ignores regs [4:7] of each operand
__device__ __forceinline__ i32x8 pad8(i32x4 v) {
  return __builtin_shufflevector(v, v, 0, 1, 2, 3, -1, -1, -1, -1);
}

// fp4 x fp4, per-lane e8m0 scale byte 0x7F (=1.0), opsel byte 0
__device__ __forceinline__ f32x4 mfma_fp4(i32x4 a, i32x4 b, f32x4 c) {
  return __builtin_amdgcn_mfma_scale_f32_16x16x128_f8f6f4(pad8(a), pad8(b), c, 4, 4, 0, 0x7F, 0,
                                                          0x7F);
}

__global__ __launch_bounds__(512, 2) void gemm_bin_fp4(const u8* __restrict__ Ag,
                                                       const u8* __restrict__ Btg,
                                                       float* __restrict__ C) {
  __shared__ u8 lds[2][4][128 * 128];

  const int tid = threadIdx.x;
  const int lane = tid & 63;
  const int wid = tid >> 6;  // 0..7
  const int wr = wid >> 2;   // 0..1 (M half)
  const int wc = wid & 3;    // 0..3 (N quarter)

  const int b = blockIdx.x;
  const int sw = (b & 7) * (gridDim.x >> 3) + (b >> 3);
  const int tiles_n = N_DIM / BN;  // 16
  const int bm = (sw / tiles_n) * BM;
  const int bn = (sw % tiles_n) * BN;

  const int l15 = lane & 15;
  const int g4 = lane >> 4;
  const int brow0 = (wc & 1) * 64;
  const int srow = lane >> 3;
  const int swz_src = (((lane & 7) ^ srow) << 4);

  auto stage = [&](int buf, int slot, const u8* gbase) {
#pragma unroll
    for (int i = 0; i < 2; ++i) {
      const u8* g = gbase + (size_t)(i * 64 + wid * 8 + srow) * KB + swz_src;
      gload_lds16(g, &lds[buf][slot][(i * 64 + wid * 8) * 128]);
    }
  };

  f32x4 acc[8][4] = {};

  {
    const u8* Abase = Ag + (size_t)bm * KB;
    const u8* Bbase = Btg + (size_t)bn * KB;
    stage(0, 0, Abase);
    stage(0, 1, Abase + (size_t)128 * KB);
    stage(0, 2, Bbase);
    stage(0, 3, Bbase + (size_t)128 * KB);
    stage(1, 2, Bbase + BKB);
    stage(1, 3, Bbase + (size_t)128 * KB + BKB);
  }
  asm volatile("s_waitcnt vmcnt(4)" ::: "memory");
  __builtin_amdgcn_s_barrier();

  i32x4 a0[4], b0[4];
  {
    const u8* As0 = &lds[0][wr][0];
    const u8* Bs0 = &lds[0][2 + (wc >> 1)][0];
#pragma unroll
    for (int m = 0; m < 4; ++m) {
      int row = m * 16 + l15;
      a0[m] = *(const i32x4*)&As0[row * 128 + ((g4 * 16) ^ ((row & 7) << 4))];
    }
#pragma unroll
    for (int n = 0; n < 4; ++n) {
      int row = brow0 + n * 16 + l15;
      b0[n] = *(const i32x4*)&Bs0[row * 128 + ((g4 * 16) ^ ((row & 7) << 4))];
    }
  }

  for (int t = 0; t < NT; ++t) {
    const int buf = t & 1;
    const u8* As = &lds[buf][wr][0];
    const u8* Bs = &lds[buf][2 + (wc >> 1)][0];
    const u8* AsN = &lds[buf ^ 1][wr][0];
    const u8* BsN = &lds[buf ^ 1][2 + (wc >> 1)][0];

    i32x4 a1[4], a2[4], a3[4], b1[4];

    // R2: a1(mh0,k1) + b1(*,k1); stage A(t+1)
#pragma unroll
    for (int m = 0; m < 4; ++m) {
      int row = m * 16 + l15;
      a1[m] = *(const i32x4*)&As[row * 128 + ((64 + g4 * 16) ^ ((row & 7) << 4))];
    }
#pragma unroll
    for (int n = 0; n < 4; ++n) {
      int row = brow0 + n * 16 + l15;
      b1[n] = *(const i32x4*)&Bs[row * 128 + ((64 + g4 * 16) ^ ((row & 7) << 4))];
    }
    if (t + 1 < NT) {
      const u8* An = Ag + (size_t)bm * KB + (t + 1) * BKB;
      stage(buf ^ 1, 0, An);
      stage(buf ^ 1, 1, An + (size_t)128 * KB);
    }
    __builtin_amdgcn_sched_barrier(0);

    // C1: a0 x b0
    __builtin_amdgcn_s_setprio(1);
#pragma unroll
    for (int m = 0; m < 4; ++m)
#pragma unroll
      for (int n = 0; n < 4; ++n)
        acc[m][n] = mfma_fp4(a0[m], b0[n], acc[m][n]);
    __builtin_amdgcn_s_setprio(0);
    __builtin_amdgcn_sched_barrier(0);

    // R3: a2(mh1,k0)
#pragma unroll
    for (int m = 0; m < 4; ++m) {
      int row = 64 + m * 16 + l15;
      a2[m] = *(const i32x4*)&As[row * 128 + ((g4 * 16) ^ ((row & 7) << 4))];
    }
    __builtin_amdgcn_sched_barrier(0);

    // C2: a1 x b1
    __builtin_amdgcn_s_setprio(1);
#pragma unroll
    for (int m = 0; m < 4; ++m)
#pragma unroll
      for (int n = 0; n < 4; ++n)
        acc[m][n] = mfma_fp4(a1[m], b1[n], acc[m][n]);
    __builtin_amdgcn_s_setprio(0);

    // MID
    asm volatile("s_waitcnt vmcnt(0)" ::: "memory");
    __builtin_amdgcn_s_barrier();

    // stage B(t+2); R4: a3(mh1,k1)
    if (t + 2 < NT) {
      const u8* Bn = Btg + (size_t)bn * KB + (t + 2) * BKB;
      stage(buf, 2, Bn);
      stage(buf, 3, Bn + (size_t)128 * KB);
    }
#pragma unroll
    for (int m = 0; m < 4; ++m) {
      int row = 64 + m * 16 + l15;
      a3[m] = *(const i32x4*)&As[row * 128 + ((64 + g4 * 16) ^ ((row & 7) << 4))];
    }
    __builtin_amdgcn_sched_barrier(0);

    // C3: a2 x b0
    __builtin_amdgcn_s_setprio(1);
#pragma unroll
    for (int m = 0; m < 4; ++m)
#pragma unroll
      for (int n = 0; n < 4; ++n)
        acc[4 + m][n] = mfma_fp4(a2[m], b0[n], acc[4 + m][n]);
    __builtin_amdgcn_s_setprio(0);
    __builtin_amdgcn_sched_barrier(0);

    // R1': preload tile t+1's a0,b0 IN PLACE
    if (t + 1 < NT) {
#pragma unroll
      for (int m = 0; m < 4; ++m) {
        int row = m * 16 + l15;
        a0[m] = *(const i32x4*)&AsN[row * 128 + ((g4 * 16) ^ ((row & 7) << 4))];
      }
#pragma unroll
      for (int n = 0; n < 4; ++n) {
        int row = brow0 + n * 16 + l15;
        b0[n] = *(const i32x4*)&BsN[row * 128 + ((g4 * 16) ^ ((row & 7) << 4))];
      }
    }
    __builtin_amdgcn_sched_barrier(0);

    // C4: a3 x b1
    __builtin_amdgcn_s_setprio(1);
#pragma unroll
    for (int m = 0; m < 4; ++m)
#pragma unroll
      for (int n = 0; n < 4; ++n)
        acc[4 + m][n] = mfma_fp4(a3[m], b1[n], acc[4 + m][n]);
    __builtin_amdgcn_s_setprio(0);

    __builtin_amdgcn_s_barrier();
  }

  // epilogue: C/D layout col = lane&15, row = (lane>>4)*4 + reg
  const int crow0 = bm + wr * 128;
  const int ccol0 = bn + wc * 64;
#pragma unroll
  for (int m = 0; m < 8; ++m)
#pragma unroll
    for (int n = 0; n < 4; ++n)
#pragma unroll
      for (int j = 0; j < 4; ++j)
        C[(size_t)(crow0 + m * 16 + g4 * 4 + j) * N_DIM + ccol0 + n * 16 + l15] = acc[m][n][j];
}

// -------- naive fallback (only if workspace is too small) --------
__global__ void naive_bin_gemm(const float* __restrict__ X, const float* __restrict__ W,
                               float* __restrict__ C) {
  int j = blockIdx.x * blockDim.x + threadIdx.x;
  int i = blockIdx.y;
  if (j >= N_DIM) return;
  float s = 0.0f;
  for (int k = 0; k < K_DIM; ++k) {
    float xv = X[(size_t)i * K_DIM + k];
    float wv = W[(size_t)k * N_DIM + j];
    float sx = (float)((xv > 0.0f) - (xv < 0.0f));
    float sw = (float)((wv > 0.0f) - (wv < 0.0f));
    s += sx * sw;
  }
  C[(size_t)i * N_DIM + j] = s;
}

extern "C" void kernel_launch(void* const* d_in, const int* in_sizes, int n_in,
                              void* d_out, int out_size, void* d_ws, size_t ws_size,
                              hipStream_t stream) {
  const float* x = (const float*)d_in[0];  // [M][K]
  const float* w = (const float*)d_in[1];  // [K][N]
  float* out = (float*)d_out;              // [M][N]

  const size_t xb_bytes = (size_t)M_DIM * KB;  // 16.8 MB
  const size_t wt_bytes = (size_t)N_DIM * KB;  // 8.4 MB

  if (ws_size >= xb_bytes + wt_bytes) {
    u8* xb = (u8*)d_ws;
    u8* wt = (u8*)((char*)d_ws + xb_bytes);

    binarize_fused<<<12288, 256, 0, stream>>>(x, w, (u32*)xb, wt);

    const int grid = (M_DIM / BM) * (N_DIM / BN);  // 32 * 16 = 512
    gemm_bin_fp4<<<grid, 512, 0, stream>>>(xb, wt, out);
  } else {
    naive_bin_gemm<<<dim3(N_DIM / 256, M_DIM), dim3(256), 0, stream>>>(x, w, out);
  }
}